// Round 1
// baseline (638.360 us; speedup 1.0000x reference)
//
#include <hip/hip_runtime.h>
#include <cstdint>
#include <cstddef>

// ---------------- graph build ----------------

__global__ void count_kernel(const int* __restrict__ dst, int E, int* __restrict__ cnt) {
  int i = blockIdx.x * blockDim.x + threadIdx.x;
  int stride = gridDim.x * blockDim.x;
  for (; i < E; i += stride) atomicAdd(&cnt[dst[i]], 1);
}

__global__ void scan1_kernel(const int* __restrict__ cnt, int n, int* __restrict__ rowptr,
                             int* __restrict__ bsums) {
  __shared__ int sm[1024];
  int t = threadIdx.x;
  int gid = blockIdx.x * 1024 + t;
  int v = (gid < n) ? cnt[gid] : 0;
  sm[t] = v;
  __syncthreads();
  for (int off = 1; off < 1024; off <<= 1) {
    int x = (t >= off) ? sm[t - off] : 0;
    __syncthreads();
    sm[t] += x;
    __syncthreads();
  }
  if (gid < n) rowptr[gid] = sm[t] - v;  // exclusive within block
  if (t == 1023) bsums[blockIdx.x] = sm[1023];
}

__global__ void scan2_kernel(int* __restrict__ bsums, int nb) {
  __shared__ int sm[1024];
  int t = threadIdx.x;
  int v = (t < nb) ? bsums[t] : 0;
  sm[t] = v;
  __syncthreads();
  for (int off = 1; off < 1024; off <<= 1) {
    int x = (t >= off) ? sm[t - off] : 0;
    __syncthreads();
    sm[t] += x;
    __syncthreads();
  }
  if (t < nb) bsums[t] = sm[t] - v;  // exclusive scan of block sums
}

__global__ void scan3_kernel(const int* __restrict__ cnt, int n, int E,
                             int* __restrict__ rowptr, const int* __restrict__ bsums,
                             int* __restrict__ cursor, float* __restrict__ dinv) {
  int i = blockIdx.x * blockDim.x + threadIdx.x;
  if (i < n) {
    int rp = rowptr[i] + bsums[i >> 10];
    rowptr[i] = rp;
    cursor[i] = rp;
    dinv[i] = rsqrtf((float)(cnt[i] + 1));  // deg includes self-loop, always >= 1
  }
  if (i == 0) rowptr[n] = E;
}

__global__ void scatter_kernel(const int* __restrict__ src, const int* __restrict__ dst, int E,
                               int* __restrict__ cursor, int* __restrict__ adj) {
  int i = blockIdx.x * blockDim.x + threadIdx.x;
  int stride = gridDim.x * blockDim.x;
  for (; i < E; i += stride) {
    int d = dst[i];
    int pos = atomicAdd(&cursor[d], 1);
    adj[pos] = src[i];
  }
}

// ---------------- GEMM: C[n,OUT] = (A*scale+shift)[n,64] @ W[64,OUT] (+bias) ----------------
// Thread-per-row; A tile staged in LDS (stride 65 -> 2-way bank alias, free);
// W[k*OUT+o] is wave-uniform -> compiler emits s_load, inner loop is v_fmac(s,v).

template <int OUT>
__launch_bounds__(128)
__global__ void gemm_kernel(const float* __restrict__ A, const float* __restrict__ W,
                            const float* __restrict__ scale, const float* __restrict__ shift,
                            const float* __restrict__ bias, float* __restrict__ C, int n) {
  __shared__ float lds[128 * 65];
  int t = threadIdx.x;
  int row0 = blockIdx.x * 128;
  int rows = n - row0; if (rows > 128) rows = 128;

  const float4* A4 = (const float4*)(A + (size_t)row0 * 64);
#pragma unroll
  for (int j = 0; j < 16; ++j) {
    int idx = t + j * 128;          // 0..2047, 16 float4/row
    int r = idx >> 4, c4 = idx & 15;
    float4 v = make_float4(0.f, 0.f, 0.f, 0.f);
    if (r < rows) v = A4[idx];
    if (scale) {
      int c = c4 * 4;
      v.x = fmaf(v.x, scale[c + 0], shift[c + 0]);
      v.y = fmaf(v.y, scale[c + 1], shift[c + 1]);
      v.z = fmaf(v.z, scale[c + 2], shift[c + 2]);
      v.w = fmaf(v.w, scale[c + 3], shift[c + 3]);
    }
    float* p = &lds[r * 65 + c4 * 4];
    p[0] = v.x; p[1] = v.y; p[2] = v.z; p[3] = v.w;
  }
  __syncthreads();

  float acc[OUT];
#pragma unroll
  for (int o = 0; o < OUT; ++o) acc[o] = 0.f;
  const float* Ar = &lds[t * 65];
  for (int k = 0; k < 64; ++k) {
    float a = Ar[k];
#pragma unroll
    for (int o = 0; o < OUT; ++o) acc[o] = fmaf(a, W[k * OUT + o], acc[o]);
  }
  __syncthreads();

  constexpr int OP = OUT + 1;
#pragma unroll
  for (int o = 0; o < OUT; ++o) {
    float v = acc[o];
    if (bias) v += bias[o];
    lds[t * OP + o] = v;
  }
  __syncthreads();

  constexpr int S4 = OUT / 4;
  float4* C4 = (float4*)(C + (size_t)row0 * OUT);
#pragma unroll
  for (int j = 0; j < S4; ++j) {
    int idx = t + j * 128;
    int r = idx / S4, c4 = idx % S4;  // S4 is power of 2
    if (r < rows) {
      float* p = &lds[r * OP + c4 * 4];
      C4[idx] = make_float4(p[0], p[1], p[2], p[3]);
    }
  }
}

// ---------------- aggregation: out[d] = relu(dinv[d]*(sum_s dinv[s]*h[s]) + dinv[d]^2*h[d] + b)
// wave-per-node, lane = feature (H=64). Fuses BN sum/sumsq accumulation.

__launch_bounds__(256)
__global__ void agg_kernel(const float* __restrict__ h, const int* __restrict__ rowptr,
                           const int* __restrict__ adj, const float* __restrict__ dinv,
                           const float* __restrict__ bias, float* __restrict__ out,
                           float* __restrict__ bnsum, float* __restrict__ bnsumsq, int n) {
  int lane = threadIdx.x & 63;
  int wave = threadIdx.x >> 6;
  int gw = blockIdx.x * 4 + wave;
  int nw = gridDim.x * 4;
  float blane = bias[lane];
  float s1 = 0.f, s2 = 0.f;

  for (int d = gw; d < n; d += nw) {
    int beg = rowptr[d], end = rowptr[d + 1];
    float di = dinv[d];
    float acc = h[(size_t)d * 64 + lane] * di;  // self-loop (x di again below)
    for (int e = beg; e < end; e += 64) {
      int m = end - e; if (m > 64) m = 64;
      int s = 0; float w = 0.f;
      if (lane < m) { int sv = adj[e + lane]; s = sv; w = dinv[sv]; }
#pragma unroll 4
      for (int j = 0; j < m; ++j) {
        int ss = __shfl(s, j);      // -> v_readlane, scalar
        float ww = __shfl(w, j);
        acc = fmaf(ww, h[(size_t)ss * 64 + lane], acc);  // coalesced 256B row gather
      }
    }
    float v = fmaf(acc, di, blane);
    v = fmaxf(v, 0.f);
    out[(size_t)d * 64 + lane] = v;
    s1 += v;
    s2 = fmaf(v, v, s2);
  }

  __shared__ float red[8][64];
  red[wave][lane] = s1;
  red[wave + 4][lane] = s2;
  __syncthreads();
  if (wave == 0) {
    float a = red[0][lane] + red[1][lane] + red[2][lane] + red[3][lane];
    float b = red[4][lane] + red[5][lane] + red[6][lane] + red[7][lane];
    atomicAdd(&bnsum[lane], a);
    atomicAdd(&bnsumsq[lane], b);
  }
}

__global__ void bnprep_kernel(const float* __restrict__ bnsum, const float* __restrict__ bnsumsq,
                              const float* __restrict__ gamma, const float* __restrict__ beta,
                              float* __restrict__ scale, float* __restrict__ shift, float invn) {
  int f = threadIdx.x;  // 64 threads
  float mu = bnsum[f] * invn;
  float var = bnsumsq[f] * invn - mu * mu;  // biased var, matches BatchNorm1d training
  float sc = gamma[f] * rsqrtf(var + 1e-5f);
  scale[f] = sc;
  shift[f] = fmaf(-mu, sc, beta[f]);
}

// ---------------- launch ----------------

extern "C" void kernel_launch(void* const* d_in, const int* in_sizes, int n_in,
                              void* d_out, int out_size, void* d_ws, size_t ws_size,
                              hipStream_t stream) {
  const float* x      = (const float*)d_in[0];
  const int*   ei     = (const int*)d_in[1];
  const float* W1     = (const float*)d_in[2];
  const float* b1     = (const float*)d_in[3];
  const float* gamma1 = (const float*)d_in[4];
  const float* beta1  = (const float*)d_in[5];
  const float* W2     = (const float*)d_in[6];
  const float* b2     = (const float*)d_in[7];
  const float* gamma2 = (const float*)d_in[8];
  const float* beta2  = (const float*)d_in[9];
  const float* Wfc    = (const float*)d_in[10];
  const float* bfc    = (const float*)d_in[11];

  int n = in_sizes[0] / 64;   // 100000
  int E = in_sizes[1] / 2;    // 1600000
  const int* src = ei;
  const int* dst = ei + E;

  char* base = (char*)d_ws;
  size_t off = 0;
  auto alloc = [&](size_t bytes) -> char* {
    char* p = base + off;
    off += (bytes + 255) & ~(size_t)255;
    return p;
  };
  int*   cnt    = (int*)alloc((size_t)n * 4);
  int*   rowptr = (int*)alloc((size_t)(n + 1) * 4);
  int*   cursor = (int*)alloc((size_t)n * 4);
  int*   adj    = (int*)alloc((size_t)E * 4);
  int*   bsums  = (int*)alloc(1024 * 4);
  float* dinv   = (float*)alloc((size_t)n * 4);
  float* bn     = (float*)alloc(512 * 4);
  // bn layout: [0]sum1 [64]sq1 [128]sum2 [192]sq2 [256]scale1 [320]shift1 [384]scale2 [448]shift2
  float* hbuf   = (float*)alloc((size_t)n * 64 * 4);
  float* rbuf   = (float*)alloc((size_t)n * 64 * 4);
  (void)ws_size; (void)n_in; (void)out_size;

  hipMemsetAsync(cnt, 0, (size_t)n * 4, stream);
  hipMemsetAsync(bn, 0, 256 * 4, stream);

  int gE = (E + 255) / 256;
  count_kernel<<<gE, 256, 0, stream>>>(dst, E, cnt);
  int nb = (n + 1023) / 1024;  // 98 <= 1024
  scan1_kernel<<<nb, 1024, 0, stream>>>(cnt, n, rowptr, bsums);
  scan2_kernel<<<1, 1024, 0, stream>>>(bsums, nb);
  scan3_kernel<<<(n + 255) / 256, 256, 0, stream>>>(cnt, n, E, rowptr, bsums, cursor, dinv);
  scatter_kernel<<<gE, 256, 0, stream>>>(src, dst, E, cursor, adj);

  int gg = (n + 127) / 128;
  // layer 1: h0 = x @ W1 ; r1 = relu(agg(h0)+b1) ; BN1 folded to scale/shift
  gemm_kernel<64><<<gg, 128, 0, stream>>>(x, W1, nullptr, nullptr, nullptr, hbuf, n);
  agg_kernel<<<2048, 256, 0, stream>>>(hbuf, rowptr, adj, dinv, b1, rbuf, bn + 0, bn + 64, n);
  bnprep_kernel<<<1, 64, 0, stream>>>(bn + 0, bn + 64, gamma1, beta1, bn + 256, bn + 320, 1.0f / n);
  // layer 2: h1 = (r1*scale1+shift1) @ W2 ; r2 = relu(agg(h1)+b2) ; BN2 folded
  gemm_kernel<64><<<gg, 128, 0, stream>>>(rbuf, W2, bn + 256, bn + 320, nullptr, hbuf, n);
  agg_kernel<<<2048, 256, 0, stream>>>(hbuf, rowptr, adj, dinv, b2, rbuf, bn + 128, bn + 192, n);
  bnprep_kernel<<<1, 64, 0, stream>>>(bn + 128, bn + 192, gamma2, beta2, bn + 384, bn + 448, 1.0f / n);
  // head: out = (r2*scale2+shift2) @ Wfc + bfc
  gemm_kernel<32><<<gg, 128, 0, stream>>>(rbuf, Wfc, bn + 384, bn + 448, bfc, (float*)d_out, n);
}

// Round 2
// 544.727 us; speedup vs baseline: 1.1719x; 1.1719x over previous
//
#include <hip/hip_runtime.h>
#include <hip/hip_bf16.h>
#include <cstdint>
#include <cstddef>

#define NS 8     // dst-space slices (one per XCD via blockIdx%8)
#define SUB 32   // blocks per slice group

static __device__ __forceinline__ unsigned pack_bf16(float a, float b) {
  __hip_bfloat16 lo = __float2bfloat16(a), hi = __float2bfloat16(b);
  unsigned short ulo = *reinterpret_cast<unsigned short*>(&lo);
  unsigned short uhi = *reinterpret_cast<unsigned short*>(&hi);
  return ((unsigned)uhi << 16) | ulo;
}

// ---------------- graph build (XCD-sliced) ----------------

// per-block LDS histogram of its dst-slice; atomic-free global phase
__launch_bounds__(1024)
__global__ void count2_kernel(const int* __restrict__ dst, int E, int n,
                              int* __restrict__ partials) {
  __shared__ int hist[12544];  // >= ceil(100000/8)
  int slice = blockIdx.x & (NS - 1), sub = blockIdx.x >> 3;
  int schunk = (n + NS - 1) / NS;
  int sbase = slice * schunk;
  int send = min(n, sbase + schunk);
  int slen = send - sbase;
  for (int l = threadIdx.x; l < slen; l += 1024) hist[l] = 0;
  __syncthreads();
  size_t ebeg = (size_t)sub * E / SUB, eend = (size_t)(sub + 1) * E / SUB;
  for (size_t i = ebeg + threadIdx.x; i < eend; i += 1024) {
    int d = dst[i] - sbase;
    if ((unsigned)d < (unsigned)slen) atomicAdd(&hist[d], 1);
  }
  __syncthreads();
  for (int l = threadIdx.x; l < slen; l += 1024)
    partials[(size_t)sub * n + sbase + l] = hist[l];
}

__global__ void reduce_cnt_kernel(const int* __restrict__ partials, int n,
                                  int* __restrict__ cnt) {
  int i = blockIdx.x * blockDim.x + threadIdx.x;
  if (i < n) {
    int s = 0;
#pragma unroll
    for (int sub = 0; sub < SUB; ++sub) s += partials[(size_t)sub * n + i];
    cnt[i] = s;
  }
}

__global__ void scan1_kernel(const int* __restrict__ cnt, int n, int* __restrict__ rowptr,
                             int* __restrict__ bsums) {
  __shared__ int sm[1024];
  int t = threadIdx.x;
  int gid = blockIdx.x * 1024 + t;
  int v = (gid < n) ? cnt[gid] : 0;
  sm[t] = v;
  __syncthreads();
  for (int off = 1; off < 1024; off <<= 1) {
    int x = (t >= off) ? sm[t - off] : 0;
    __syncthreads();
    sm[t] += x;
    __syncthreads();
  }
  if (gid < n) rowptr[gid] = sm[t] - v;  // exclusive within block
  if (t == 1023) bsums[blockIdx.x] = sm[1023];
}

__global__ void scan2_kernel(int* __restrict__ bsums, int nb) {
  __shared__ int sm[1024];
  int t = threadIdx.x;
  int v = (t < nb) ? bsums[t] : 0;
  sm[t] = v;
  __syncthreads();
  for (int off = 1; off < 1024; off <<= 1) {
    int x = (t >= off) ? sm[t - off] : 0;
    __syncthreads();
    sm[t] += x;
    __syncthreads();
  }
  if (t < nb) bsums[t] = sm[t] - v;
}

__global__ void scan3_kernel(const int* __restrict__ cnt, int n, int E,
                             int* __restrict__ rowptr, const int* __restrict__ bsums,
                             int* __restrict__ cursor, float* __restrict__ dinv) {
  int i = blockIdx.x * blockDim.x + threadIdx.x;
  if (i < n) {
    int rp = rowptr[i] + bsums[i >> 10];
    rowptr[i] = rp;
    cursor[i] = rp;
    dinv[i] = rsqrtf((float)(cnt[i] + 1));  // deg includes self-loop
  }
  if (i == 0) rowptr[n] = E;
}

// XCD-sliced scatter: each slice group scans all edges, writes only its
// contiguous adj region -> full-line writebacks, no cross-XCD line thrash
__launch_bounds__(1024)
__global__ void scatter2_kernel(const int* __restrict__ src, const int* __restrict__ dst,
                                int E, int n, int* __restrict__ cursor, int* __restrict__ adj) {
  int slice = blockIdx.x & (NS - 1), sub = blockIdx.x >> 3;
  int schunk = (n + NS - 1) / NS;
  int sbase = slice * schunk;
  int send = min(n, sbase + schunk);
  size_t ebeg = (size_t)sub * E / SUB, eend = (size_t)(sub + 1) * E / SUB;
  for (size_t i = ebeg + threadIdx.x; i < eend; i += 1024) {
    int d = dst[i];
    if (d >= sbase && d < send) {
      int pos = atomicAdd(&cursor[d], 1);
      adj[pos] = src[i];
    }
  }
}

// ---------------- GEMM: C[n,OUT] = (A*scale+shift)[n,64] @ W[64,OUT] (+bias) ----------------

template <int OUT, bool BF16OUT>
__launch_bounds__(128)
__global__ void gemm_kernel(const float* __restrict__ A, const float* __restrict__ W,
                            const float* __restrict__ scale, const float* __restrict__ shift,
                            const float* __restrict__ bias, void* __restrict__ Cout, int n) {
  __shared__ float lds[128 * 65];
  int t = threadIdx.x;
  int row0 = blockIdx.x * 128;
  int rows = n - row0; if (rows > 128) rows = 128;

  const float4* A4 = (const float4*)(A + (size_t)row0 * 64);
#pragma unroll
  for (int j = 0; j < 16; ++j) {
    int idx = t + j * 128;
    int r = idx >> 4, c4 = idx & 15;
    float4 v = make_float4(0.f, 0.f, 0.f, 0.f);
    if (r < rows) v = A4[idx];
    if (scale) {
      int c = c4 * 4;
      v.x = fmaf(v.x, scale[c + 0], shift[c + 0]);
      v.y = fmaf(v.y, scale[c + 1], shift[c + 1]);
      v.z = fmaf(v.z, scale[c + 2], shift[c + 2]);
      v.w = fmaf(v.w, scale[c + 3], shift[c + 3]);
    }
    float* p = &lds[r * 65 + c4 * 4];
    p[0] = v.x; p[1] = v.y; p[2] = v.z; p[3] = v.w;
  }
  __syncthreads();

  float acc[OUT];
#pragma unroll
  for (int o = 0; o < OUT; ++o) acc[o] = 0.f;
  const float* Ar = &lds[t * 65];
  for (int k = 0; k < 64; ++k) {
    float a = Ar[k];
#pragma unroll
    for (int o = 0; o < OUT; ++o) acc[o] = fmaf(a, W[k * OUT + o], acc[o]);
  }
  if (bias) {
#pragma unroll
    for (int o = 0; o < OUT; ++o) acc[o] += bias[o];
  }
  __syncthreads();

  if (BF16OUT) {
    unsigned* ldsu = (unsigned*)lds;
    constexpr int OPU = OUT / 2 + 1;  // 33 for OUT=64
#pragma unroll
    for (int o2 = 0; o2 < OUT / 2; ++o2)
      ldsu[t * OPU + o2] = pack_bf16(acc[2 * o2], acc[2 * o2 + 1]);
    __syncthreads();
    constexpr int S4 = OUT / 8;  // uint4 per row
    uint4* C4 = (uint4*)((__hip_bfloat16*)Cout + (size_t)row0 * OUT);
#pragma unroll
    for (int j = 0; j < S4; ++j) {
      int idx = t + j * 128;
      int r = idx / S4, c = idx % S4;
      if (r < rows) {
        unsigned* p = &ldsu[r * OPU + c * 4];
        uint4 v; v.x = p[0]; v.y = p[1]; v.z = p[2]; v.w = p[3];
        C4[idx] = v;
      }
    }
  } else {
    constexpr int OP = OUT + 1;
#pragma unroll
    for (int o = 0; o < OUT; ++o) lds[t * OP + o] = acc[o];
    __syncthreads();
    constexpr int S4 = OUT / 4;
    float4* C4 = (float4*)((float*)Cout + (size_t)row0 * OUT);
#pragma unroll
    for (int j = 0; j < S4; ++j) {
      int idx = t + j * 128;
      int r = idx / S4, c4 = idx % S4;
      if (r < rows) {
        float* p = &lds[r * OP + c4 * 4];
        C4[idx] = make_float4(p[0], p[1], p[2], p[3]);
      }
    }
  }
}

// ---------------- aggregation (bf16 gather table) ----------------
// out[d] = relu(dinv[d]*(sum_s dinv[s]*h[s]) + dinv[d]^2*h[d] + b); fused BN stats

__launch_bounds__(256)
__global__ void agg_kernel(const __hip_bfloat16* __restrict__ h, const int* __restrict__ rowptr,
                           const int* __restrict__ adj, const float* __restrict__ dinv,
                           const float* __restrict__ bias, float* __restrict__ out,
                           float* __restrict__ bnsum, float* __restrict__ bnsumsq, int n) {
  int lane = threadIdx.x & 63;
  int wave = threadIdx.x >> 6;
  int gw = blockIdx.x * 4 + wave;
  int nw = gridDim.x * 4;
  float blane = bias[lane];
  float s1 = 0.f, s2 = 0.f;

  for (int d = gw; d < n; d += nw) {
    int beg = rowptr[d], end = rowptr[d + 1];
    float di = dinv[d];
    float acc = __bfloat162float(h[(size_t)d * 64 + lane]) * di;  // self-loop
    for (int e = beg; e < end; e += 64) {
      int m = end - e; if (m > 64) m = 64;
      int s = 0; float w = 0.f;
      if (lane < m) { int sv = adj[e + lane]; s = sv; w = dinv[sv]; }
#pragma unroll 4
      for (int j = 0; j < m; ++j) {
        int ss = __shfl(s, j);
        float ww = __shfl(w, j);
        acc = fmaf(ww, __bfloat162float(h[(size_t)ss * 64 + lane]), acc);  // 128B row gather
      }
    }
    float v = fmaf(acc, di, blane);
    v = fmaxf(v, 0.f);
    out[(size_t)d * 64 + lane] = v;
    s1 += v;
    s2 = fmaf(v, v, s2);
  }

  __shared__ float red[8][64];
  red[wave][lane] = s1;
  red[wave + 4][lane] = s2;
  __syncthreads();
  if (wave == 0) {
    float a = red[0][lane] + red[1][lane] + red[2][lane] + red[3][lane];
    float b = red[4][lane] + red[5][lane] + red[6][lane] + red[7][lane];
    atomicAdd(&bnsum[lane], a);
    atomicAdd(&bnsumsq[lane], b);
  }
}

__global__ void bnprep_kernel(const float* __restrict__ bnsum, const float* __restrict__ bnsumsq,
                              const float* __restrict__ gamma, const float* __restrict__ beta,
                              float* __restrict__ scale, float* __restrict__ shift, float invn) {
  int f = threadIdx.x;  // 64 threads
  float mu = bnsum[f] * invn;
  float var = bnsumsq[f] * invn - mu * mu;  // biased var (BatchNorm1d training)
  float sc = gamma[f] * rsqrtf(var + 1e-5f);
  scale[f] = sc;
  shift[f] = fmaf(-mu, sc, beta[f]);
}

// ---------------- launch ----------------

extern "C" void kernel_launch(void* const* d_in, const int* in_sizes, int n_in,
                              void* d_out, int out_size, void* d_ws, size_t ws_size,
                              hipStream_t stream) {
  const float* x      = (const float*)d_in[0];
  const int*   ei     = (const int*)d_in[1];
  const float* W1     = (const float*)d_in[2];
  const float* b1     = (const float*)d_in[3];
  const float* gamma1 = (const float*)d_in[4];
  const float* beta1  = (const float*)d_in[5];
  const float* W2     = (const float*)d_in[6];
  const float* b2     = (const float*)d_in[7];
  const float* gamma2 = (const float*)d_in[8];
  const float* beta2  = (const float*)d_in[9];
  const float* Wfc    = (const float*)d_in[10];
  const float* bfc    = (const float*)d_in[11];

  int n = in_sizes[0] / 64;   // 100000
  int E = in_sizes[1] / 2;    // 1600000
  const int* src = ei;
  const int* dst = ei + E;

  char* base = (char*)d_ws;
  size_t off = 0;
  auto alloc = [&](size_t bytes) -> char* {
    char* p = base + off;
    off += (bytes + 255) & ~(size_t)255;
    return p;
  };
  int*   cnt    = (int*)alloc((size_t)n * 4);
  int*   rowptr = (int*)alloc((size_t)(n + 1) * 4);
  int*   cursor = (int*)alloc((size_t)n * 4);
  int*   adj    = (int*)alloc((size_t)E * 4);
  int*   bsums  = (int*)alloc(1024 * 4);
  float* dinv   = (float*)alloc((size_t)n * 4);
  float* bn     = (float*)alloc(512 * 4);
  // bn: [0]sum1 [64]sq1 [128]sum2 [192]sq2 [256]scale1 [320]shift1 [384]scale2 [448]shift2
  __hip_bfloat16* hbuf = (__hip_bfloat16*)alloc((size_t)n * 64 * 2);
  float* rbuf   = (float*)alloc((size_t)n * 64 * 4);
  int* partials = (int*)rbuf;  // 32*n*4 = 12.8MB <= rbuf(25.6MB); dead before agg1 writes rbuf
  (void)ws_size; (void)n_in; (void)out_size;

  hipMemsetAsync(bn, 0, 256 * 4, stream);

  count2_kernel<<<NS * SUB, 1024, 0, stream>>>(dst, E, n, partials);
  reduce_cnt_kernel<<<(n + 255) / 256, 256, 0, stream>>>(partials, n, cnt);
  int nb = (n + 1023) / 1024;
  scan1_kernel<<<nb, 1024, 0, stream>>>(cnt, n, rowptr, bsums);
  scan2_kernel<<<1, 1024, 0, stream>>>(bsums, nb);
  scan3_kernel<<<(n + 255) / 256, 256, 0, stream>>>(cnt, n, E, rowptr, bsums, cursor, dinv);
  scatter2_kernel<<<NS * SUB, 1024, 0, stream>>>(src, dst, E, n, cursor, adj);

  int gg = (n + 127) / 128;
  // layer 1
  gemm_kernel<64, true><<<gg, 128, 0, stream>>>(x, W1, nullptr, nullptr, nullptr, hbuf, n);
  agg_kernel<<<2048, 256, 0, stream>>>(hbuf, rowptr, adj, dinv, b1, rbuf, bn + 0, bn + 64, n);
  bnprep_kernel<<<1, 64, 0, stream>>>(bn + 0, bn + 64, gamma1, beta1, bn + 256, bn + 320, 1.0f / n);
  // layer 2
  gemm_kernel<64, true><<<gg, 128, 0, stream>>>(rbuf, W2, bn + 256, bn + 320, nullptr, hbuf, n);
  agg_kernel<<<2048, 256, 0, stream>>>(hbuf, rowptr, adj, dinv, b2, rbuf, bn + 128, bn + 192, n);
  bnprep_kernel<<<1, 64, 0, stream>>>(bn + 128, bn + 192, gamma2, beta2, bn + 384, bn + 448, 1.0f / n);
  // head
  gemm_kernel<32, false><<<gg, 128, 0, stream>>>(rbuf, Wfc, bn + 384, bn + 448, bfc, d_out, n);
}

// Round 3
// 443.540 us; speedup vs baseline: 1.4392x; 1.2281x over previous
//
#include <hip/hip_runtime.h>
#include <hip/hip_bf16.h>
#include <cstdint>
#include <cstddef>

#define NS 8     // dst-space slices (one per XCD via blockIdx%8)
#define SUB 32   // blocks per slice group

static __device__ __forceinline__ unsigned pack_bf16(float a, float b) {
  __hip_bfloat16 lo = __float2bfloat16(a), hi = __float2bfloat16(b);
  unsigned short ulo = *reinterpret_cast<unsigned short*>(&lo);
  unsigned short uhi = *reinterpret_cast<unsigned short*>(&hi);
  return ((unsigned)uhi << 16) | ulo;
}
static __device__ __forceinline__ float blo(unsigned u) {
  union { unsigned q; float f; } x; x.q = u << 16; return x.f;
}
static __device__ __forceinline__ float bhi(unsigned u) {
  union { unsigned q; float f; } x; x.q = u & 0xffff0000u; return x.f;
}

// ---------------- graph build (XCD-sliced) ----------------

__launch_bounds__(1024)
__global__ void count2_kernel(const int* __restrict__ dst, int E, int n,
                              int* __restrict__ partials) {
  __shared__ int hist[12544];  // >= ceil(100000/8)
  int slice = blockIdx.x & (NS - 1), sub = blockIdx.x >> 3;
  int schunk = (n + NS - 1) / NS;
  int sbase = slice * schunk;
  int send = min(n, sbase + schunk);
  int slen = send - sbase;
  for (int l = threadIdx.x; l < slen; l += 1024) hist[l] = 0;
  __syncthreads();
  size_t ebeg = (size_t)sub * E / SUB, eend = (size_t)(sub + 1) * E / SUB;
  for (size_t i = ebeg + threadIdx.x; i < eend; i += 1024) {
    int d = dst[i] - sbase;
    if ((unsigned)d < (unsigned)slen) atomicAdd(&hist[d], 1);
  }
  __syncthreads();
  for (int l = threadIdx.x; l < slen; l += 1024)
    partials[(size_t)sub * n + sbase + l] = hist[l];
}

__global__ void reduce_cnt_kernel(const int* __restrict__ partials, int n,
                                  int* __restrict__ cnt) {
  int i = blockIdx.x * blockDim.x + threadIdx.x;
  if (i < n) {
    int s = 0;
#pragma unroll
    for (int sub = 0; sub < SUB; ++sub) s += partials[(size_t)sub * n + i];
    cnt[i] = s;
  }
}

__global__ void scan1_kernel(const int* __restrict__ cnt, int n, int* __restrict__ rowptr,
                             int* __restrict__ bsums) {
  __shared__ int sm[1024];
  int t = threadIdx.x;
  int gid = blockIdx.x * 1024 + t;
  int v = (gid < n) ? cnt[gid] : 0;
  sm[t] = v;
  __syncthreads();
  for (int off = 1; off < 1024; off <<= 1) {
    int x = (t >= off) ? sm[t - off] : 0;
    __syncthreads();
    sm[t] += x;
    __syncthreads();
  }
  if (gid < n) rowptr[gid] = sm[t] - v;
  if (t == 1023) bsums[blockIdx.x] = sm[1023];
}

__global__ void scan2_kernel(int* __restrict__ bsums, int nb) {
  __shared__ int sm[1024];
  int t = threadIdx.x;
  int v = (t < nb) ? bsums[t] : 0;
  sm[t] = v;
  __syncthreads();
  for (int off = 1; off < 1024; off <<= 1) {
    int x = (t >= off) ? sm[t - off] : 0;
    __syncthreads();
    sm[t] += x;
    __syncthreads();
  }
  if (t < nb) bsums[t] = sm[t] - v;
}

__global__ void scan3_kernel(const int* __restrict__ cnt, int n, int E,
                             int* __restrict__ rowptr, const int* __restrict__ bsums,
                             int* __restrict__ cursor, float* __restrict__ dinv) {
  int i = blockIdx.x * blockDim.x + threadIdx.x;
  if (i < n) {
    int rp = rowptr[i] + bsums[i >> 10];
    rowptr[i] = rp;
    cursor[i] = rp;
    dinv[i] = rsqrtf((float)(cnt[i] + 1));  // deg includes self-loop
  }
  if (i == 0) rowptr[n] = E;
}

__launch_bounds__(1024)
__global__ void scatter2_kernel(const int* __restrict__ src, const int* __restrict__ dst,
                                int E, int n, int* __restrict__ cursor, int* __restrict__ adj) {
  int slice = blockIdx.x & (NS - 1), sub = blockIdx.x >> 3;
  int schunk = (n + NS - 1) / NS;
  int sbase = slice * schunk;
  int send = min(n, sbase + schunk);
  size_t ebeg = (size_t)sub * E / SUB, eend = (size_t)(sub + 1) * E / SUB;
  for (size_t i = ebeg + threadIdx.x; i < eend; i += 1024) {
    int d = dst[i];
    if (d >= sbase && d < send) {
      int pos = atomicAdd(&cursor[d], 1);
      adj[pos] = src[i];
    }
  }
}

// ---------------- GEMM: C[n,OUT] = (A*scale+shift)[n,64] @ W[64,OUT] (+bias, *rowscale) ------

template <int OUT, bool BF16OUT>
__launch_bounds__(128)
__global__ void gemm_kernel(const float* __restrict__ A, const float* __restrict__ W,
                            const float* __restrict__ scale, const float* __restrict__ shift,
                            const float* __restrict__ bias, const float* __restrict__ rowscale,
                            void* __restrict__ Cout, int n) {
  __shared__ float lds[128 * 65];
  int t = threadIdx.x;
  int row0 = blockIdx.x * 128;
  int rows = n - row0; if (rows > 128) rows = 128;

  const float4* A4 = (const float4*)(A + (size_t)row0 * 64);
#pragma unroll
  for (int j = 0; j < 16; ++j) {
    int idx = t + j * 128;
    int r = idx >> 4, c4 = idx & 15;
    float4 v = make_float4(0.f, 0.f, 0.f, 0.f);
    if (r < rows) v = A4[idx];
    if (scale) {
      int c = c4 * 4;
      v.x = fmaf(v.x, scale[c + 0], shift[c + 0]);
      v.y = fmaf(v.y, scale[c + 1], shift[c + 1]);
      v.z = fmaf(v.z, scale[c + 2], shift[c + 2]);
      v.w = fmaf(v.w, scale[c + 3], shift[c + 3]);
    }
    float* p = &lds[r * 65 + c4 * 4];
    p[0] = v.x; p[1] = v.y; p[2] = v.z; p[3] = v.w;
  }
  __syncthreads();

  float acc[OUT];
#pragma unroll
  for (int o = 0; o < OUT; ++o) acc[o] = 0.f;
  const float* Ar = &lds[t * 65];
  for (int k = 0; k < 64; ++k) {
    float a = Ar[k];
#pragma unroll
    for (int o = 0; o < OUT; ++o) acc[o] = fmaf(a, W[k * OUT + o], acc[o]);
  }
  if (rowscale) {
    int r = row0 + t; if (r >= n) r = n - 1;
    float rs = rowscale[r];
#pragma unroll
    for (int o = 0; o < OUT; ++o) acc[o] *= rs;
  }
  if (bias) {
#pragma unroll
    for (int o = 0; o < OUT; ++o) acc[o] += bias[o];
  }
  __syncthreads();

  if (BF16OUT) {
    unsigned* ldsu = (unsigned*)lds;
    constexpr int OPU = OUT / 2 + 1;
#pragma unroll
    for (int o2 = 0; o2 < OUT / 2; ++o2)
      ldsu[t * OPU + o2] = pack_bf16(acc[2 * o2], acc[2 * o2 + 1]);
    __syncthreads();
    constexpr int S4 = OUT / 8;
    uint4* C4 = (uint4*)((__hip_bfloat16*)Cout + (size_t)row0 * OUT);
#pragma unroll
    for (int j = 0; j < S4; ++j) {
      int idx = t + j * 128;
      int r = idx / S4, c = idx % S4;
      if (r < rows) {
        unsigned* p = &ldsu[r * OPU + c * 4];
        uint4 v; v.x = p[0]; v.y = p[1]; v.z = p[2]; v.w = p[3];
        C4[idx] = v;
      }
    }
  } else {
    constexpr int OP = OUT + 1;
#pragma unroll
    for (int o = 0; o < OUT; ++o) lds[t * OP + o] = acc[o];
    __syncthreads();
    constexpr int S4 = OUT / 4;
    float4* C4 = (float4*)((float*)Cout + (size_t)row0 * OUT);
#pragma unroll
    for (int j = 0; j < S4; ++j) {
      int idx = t + j * 128;
      int r = idx / S4, c4 = idx % S4;
      if (r < rows) {
        float* p = &lds[r * OP + c4 * 4];
        C4[idx] = make_float4(p[0], p[1], p[2], p[3]);
      }
    }
  }
}

// ---------------- aggregation v2 ----------------
// g[i] = bf16(h[i]*dinv[i]) precomputed in GEMM. out[d] = relu(dinv[d]*Sum g[s] + b),
// sum includes self (s=d). 8 nodes per wave: 8-lane group per node, 16B/lane (8 bf16),
// one gather instruction = 8 full 128B rows. No shfl/dinv in the edge loop -> high MLP.

__launch_bounds__(256, 8)
__global__ void agg_kernel(const __hip_bfloat16* __restrict__ g, const int* __restrict__ rowptr,
                           const int* __restrict__ adj, const float* __restrict__ dinv,
                           const float* __restrict__ bias, float* __restrict__ out,
                           float* __restrict__ bnsum, float* __restrict__ bnsumsq, int n) {
  const int tid = threadIdx.x;
  const int lane = tid & 63;
  const int wave = tid >> 6;
  const int grp = lane >> 3;   // node slot 0..7
  const int sub = lane & 7;    // feature slice: features sub*8..sub*8+7
  const int gw = blockIdx.x * 4 + wave;
  const int nslot = gridDim.x * 4 * 8;

  float bias8[8];
  const float4* bp = (const float4*)(bias + sub * 8);
  float4 b0 = bp[0], b1 = bp[1];
  bias8[0]=b0.x; bias8[1]=b0.y; bias8[2]=b0.z; bias8[3]=b0.w;
  bias8[4]=b1.x; bias8[5]=b1.y; bias8[6]=b1.z; bias8[7]=b1.w;

  float s1[8], s2[8];
#pragma unroll
  for (int j = 0; j < 8; ++j) { s1[j] = 0.f; s2[j] = 0.f; }

  const unsigned short* gu = (const unsigned short*)g;

  for (int d0 = gw * 8; d0 < n; d0 += nslot) {
    int d = d0 + grp;
    bool nvalid = d < n;
    int dd = nvalid ? d : (n - 1);
    int beg = rowptr[dd];
    int deg = rowptr[dd + 1] - beg;
    int k = nvalid ? (deg + 1) : 0;  // +1 virtual self-edge
    float di = dinv[dd];

    float acc[8];
#pragma unroll
    for (int j = 0; j < 8; ++j) acc[j] = 0.f;

    int kmax = k;
    kmax = max(kmax, __shfl_xor(kmax, 8));
    kmax = max(kmax, __shfl_xor(kmax, 16));
    kmax = max(kmax, __shfl_xor(kmax, 32));

    for (int j0 = 0; j0 < kmax; j0 += 4) {
#pragma unroll
      for (int u = 0; u < 4; ++u) {
        int idx = j0 + u;
        if (idx < k) {
          int s = (idx < deg) ? adj[beg + idx] : dd;
          const uint4 v = *(const uint4*)(gu + (((size_t)s) << 6) + sub * 8);
          acc[0] += blo(v.x); acc[1] += bhi(v.x);
          acc[2] += blo(v.y); acc[3] += bhi(v.y);
          acc[4] += blo(v.z); acc[5] += bhi(v.z);
          acc[6] += blo(v.w); acc[7] += bhi(v.w);
        }
      }
    }

    if (nvalid) {
      float o[8];
#pragma unroll
      for (int j = 0; j < 8; ++j) {
        float v = fmaf(acc[j], di, bias8[j]);
        v = fmaxf(v, 0.f);
        o[j] = v;
        s1[j] += v;
        s2[j] = fmaf(v, v, s2[j]);
      }
      float4* op = (float4*)(out + (((size_t)d) << 6) + sub * 8);
      op[0] = make_float4(o[0], o[1], o[2], o[3]);
      op[1] = make_float4(o[4], o[5], o[6], o[7]);
    }
  }

  // BN stats: block reduce (thread t holds features (t&7)*8+j)
  __shared__ float red1[2048], red2[2048];  // 256 threads x 8
#pragma unroll
  for (int j = 0; j < 8; ++j) { red1[tid * 8 + j] = s1[j]; red2[tid * 8 + j] = s2[j]; }
  __syncthreads();
  if (tid < 64) {
    int sgrp = tid >> 3, j = tid & 7;
    float a = 0.f, b = 0.f;
#pragma unroll
    for (int i = 0; i < 32; ++i) {
      int t = sgrp + (i << 3);
      a += red1[t * 8 + j];
      b += red2[t * 8 + j];
    }
    atomicAdd(&bnsum[tid], a);
    atomicAdd(&bnsumsq[tid], b);
  }
}

__global__ void bnprep_kernel(const float* __restrict__ bnsum, const float* __restrict__ bnsumsq,
                              const float* __restrict__ gamma, const float* __restrict__ beta,
                              float* __restrict__ scale, float* __restrict__ shift, float invn) {
  int f = threadIdx.x;  // 64 threads
  float mu = bnsum[f] * invn;
  float var = bnsumsq[f] * invn - mu * mu;  // biased var (BatchNorm1d training)
  float sc = gamma[f] * rsqrtf(var + 1e-5f);
  scale[f] = sc;
  shift[f] = fmaf(-mu, sc, beta[f]);
}

// ---------------- launch ----------------

extern "C" void kernel_launch(void* const* d_in, const int* in_sizes, int n_in,
                              void* d_out, int out_size, void* d_ws, size_t ws_size,
                              hipStream_t stream) {
  const float* x      = (const float*)d_in[0];
  const int*   ei     = (const int*)d_in[1];
  const float* W1     = (const float*)d_in[2];
  const float* b1     = (const float*)d_in[3];
  const float* gamma1 = (const float*)d_in[4];
  const float* beta1  = (const float*)d_in[5];
  const float* W2     = (const float*)d_in[6];
  const float* b2     = (const float*)d_in[7];
  const float* gamma2 = (const float*)d_in[8];
  const float* beta2  = (const float*)d_in[9];
  const float* Wfc    = (const float*)d_in[10];
  const float* bfc    = (const float*)d_in[11];

  int n = in_sizes[0] / 64;   // 100000
  int E = in_sizes[1] / 2;    // 1600000
  const int* src = ei;
  const int* dst = ei + E;

  char* base = (char*)d_ws;
  size_t off = 0;
  auto alloc = [&](size_t bytes) -> char* {
    char* p = base + off;
    off += (bytes + 255) & ~(size_t)255;
    return p;
  };
  int*   cnt    = (int*)alloc((size_t)n * 4);
  int*   rowptr = (int*)alloc((size_t)(n + 1) * 4);
  int*   cursor = (int*)alloc((size_t)n * 4);
  int*   adj    = (int*)alloc((size_t)E * 4);
  int*   bsums  = (int*)alloc(1024 * 4);
  float* dinv   = (float*)alloc((size_t)n * 4);
  float* bn     = (float*)alloc(512 * 4);
  // bn: [0]sum1 [64]sq1 [128]sum2 [192]sq2 [256]scale1 [320]shift1 [384]scale2 [448]shift2
  __hip_bfloat16* hbuf = (__hip_bfloat16*)alloc((size_t)n * 64 * 2);
  float* rbuf   = (float*)alloc((size_t)n * 64 * 4);
  int* partials = (int*)rbuf;  // 12.8MB <= rbuf(25.6MB); dead before agg1 writes rbuf
  (void)ws_size; (void)n_in; (void)out_size;

  hipMemsetAsync(bn, 0, 256 * 4, stream);

  count2_kernel<<<NS * SUB, 1024, 0, stream>>>(dst, E, n, partials);
  reduce_cnt_kernel<<<(n + 255) / 256, 256, 0, stream>>>(partials, n, cnt);
  int nb = (n + 1023) / 1024;
  scan1_kernel<<<nb, 1024, 0, stream>>>(cnt, n, rowptr, bsums);
  scan2_kernel<<<1, 1024, 0, stream>>>(bsums, nb);
  scan3_kernel<<<(n + 255) / 256, 256, 0, stream>>>(cnt, n, E, rowptr, bsums, cursor, dinv);
  scatter2_kernel<<<NS * SUB, 1024, 0, stream>>>(src, dst, E, n, cursor, adj);

  int gg = (n + 127) / 128;
  // layer 1: g = bf16((x@W1)*dinv) ; rbuf = relu(dinv*Sum g + b1) ; BN1 -> scale/shift
  gemm_kernel<64, true><<<gg, 128, 0, stream>>>(x, W1, nullptr, nullptr, nullptr, dinv, hbuf, n);
  agg_kernel<<<2048, 256, 0, stream>>>(hbuf, rowptr, adj, dinv, b1, rbuf, bn + 0, bn + 64, n);
  bnprep_kernel<<<1, 64, 0, stream>>>(bn + 0, bn + 64, gamma1, beta1, bn + 256, bn + 320, 1.0f / n);
  // layer 2
  gemm_kernel<64, true><<<gg, 128, 0, stream>>>(rbuf, W2, bn + 256, bn + 320, nullptr, dinv, hbuf, n);
  agg_kernel<<<2048, 256, 0, stream>>>(hbuf, rowptr, adj, dinv, b2, rbuf, bn + 128, bn + 192, n);
  bnprep_kernel<<<1, 64, 0, stream>>>(bn + 128, bn + 192, gamma2, beta2, bn + 384, bn + 448, 1.0f / n);
  // head
  gemm_kernel<32, false><<<gg, 128, 0, stream>>>(rbuf, Wfc, bn + 384, bn + 448, bfc, nullptr, d_out, n);
}